// Round 21
// baseline (96.464 us; speedup 1.0000x reference)
//
#include <hip/hip_runtime.h>
#include <hip/hip_bf16.h>
#include <stdint.h>

#define NROWS 32768
#define MCOLS 8192
#define DDIM  256

#define BM 128            // rows per workgroup; block sweeps ALL cols
#define BN 64             // cols per iteration (4 strips x 16)
#define NT (MCOLS/BN)     // 128 iterations
#define NWG (NROWS/BM)    // 256 workgroups = 1 per CU

typedef __attribute__((ext_vector_type(8))) int   int8v;
typedef __attribute__((ext_vector_type(4))) int   int4v;
typedef __attribute__((ext_vector_type(4))) float f32x4;

#define AS1 __attribute__((address_space(1)))
#define AS3 __attribute__((address_space(3)))

// LDS map (bytes): [0,65536) = 8 waves x 8KB private dbuf B
//                  [65536,98304)  = Cs (all 8192 cj)
//                  [98304,100352) = Rw[4][128] strip-min merge
//                  [100352,100368) = part
//                  [100368,100880) = xhh[128] (0.5*||x||^2 per block row)
#define CS_OFF   65536
#define RW_OFF   98304
#define PART_OFF 100352
#define XH_OFF   100368

// pack 4 f32 -> 4 fp8 e4m3 (OCP) via HW converter (RNE, saturating)
__device__ __forceinline__ uint32_t pk4_fp8(float4 v) {
  int p = __builtin_amdgcn_cvt_pk_fp8_f32(v.x, v.y, 0, false);
  p = __builtin_amdgcn_cvt_pk_fp8_f32(v.z, v.w, p, true);
  return (uint32_t)p;
}
__device__ __forceinline__ f32x4 vmin4(f32x4 x, f32x4 y) {
  f32x4 r;
  r[0] = fminf(x[0], y[0]); r[1] = fminf(x[1], y[1]);
  r[2] = fminf(x[2], y[2]); r[3] = fminf(x[3], y[3]);
  return r;
}

// ---- K1: Y-only prep. Yq = row-major fp8; cbuf = 0.5||y||^2 - psi;
//          block 0 additionally: psum = mean(psi), zero sum_accum + ticket.
__global__ void k_prepY(const float* __restrict__ Y, const float* __restrict__ psi,
                        uint32_t* __restrict__ Yq, float* __restrict__ cbuf,
                        float* __restrict__ psum, float* __restrict__ sum_accum,
                        uint32_t* __restrict__ ticket)
{
  if (blockIdx.x == 0) {
    __shared__ float sh[4];
    float s = 0.f;
    for (int i = threadIdx.x; i < MCOLS; i += 256) s += psi[i];
    #pragma unroll
    for (int m = 32; m >= 1; m >>= 1) s += __shfl_xor(s, m);
    if ((threadIdx.x & 63) == 0) sh[threadIdx.x >> 6] = s;
    __syncthreads();
    if (threadIdx.x == 0) {
      psum[0] = (sh[0] + sh[1] + sh[2] + sh[3]) / (float)MCOLS;
      sum_accum[0] = 0.0f;
      ticket[0] = 0u;
    }
  }
  const int lane = threadIdx.x & 63;
  const int gw = (blockIdx.x * blockDim.x + threadIdx.x) >> 6;
  const int nw = (gridDim.x * blockDim.x) >> 6;
  for (int r = gw; r < MCOLS; r += nw) {
    float4 v = ((const float4*)(Y + (size_t)r * DDIM))[lane];
    Yq[(size_t)r * 64 + lane] = pk4_fp8(v);
    float s = v.x*v.x + v.y*v.y + v.z*v.z + v.w*v.w;
    #pragma unroll
    for (int m = 32; m >= 1; m >>= 1) s += __shfl_xor(s, m);
    if (lane == 0) cbuf[r] = 0.5f * s - psi[r];
  }
}

// stage this wave's OWN 16-col strip of tile t_ (4 KB) into its private LDS
// half h_ (0/4096). XOR involution: LDS[c][q] = Yq[col][q ^ (c&15)]; dest
// linear (rule #21). srcG[g] precomputed per-lane for t=0; +t*16384 per tile.
#define STAGE(t_, h_) do {                                                      \
    _Pragma("unroll") for (int _g = 0; _g < 4; ++_g)                            \
      __builtin_amdgcn_global_load_lds(                                         \
          (const AS1 uint32_t*)(srcG[_g] + (size_t)(t_) * 16384),               \
          (AS3 uint32_t*)(ldsB + wbase + (h_) + _g * 1024), 16, 0, 0);          \
  } while (0)

// one body (r20 schedule): read own strip frags (4 b128); 8 MFMA with
// C-init = cj (preloaded register) into ACC; stage t_+2 into half consumed.
#define ITERC(t_, h_, ACC, cjv) do {                                            \
    asm volatile("s_waitcnt vmcnt(4)" ::: "memory");                            \
    int8v bf0, bf1;                                                             \
    {                                                                           \
      const char* _b = ldsB + wbase + (h_) + c15 * 256;                         \
      const int4v _l0 = *(const int4v*)(_b + (((w4 * 2 + 0) ^ c15) << 4));      \
      const int4v _h0 = *(const int4v*)(_b + (((w4 * 2 + 1) ^ c15) << 4));      \
      const int4v _l1 = *(const int4v*)(_b + (((8 + w4 * 2 + 0) ^ c15) << 4));  \
      const int4v _h1 = *(const int4v*)(_b + (((8 + w4 * 2 + 1) ^ c15) << 4));  \
      bf0 = (int8v){_l0[0],_l0[1],_l0[2],_l0[3],_h0[0],_h0[1],_h0[2],_h0[3]};   \
      bf1 = (int8v){_l1[0],_l1[1],_l1[2],_l1[3],_h1[0],_h1[1],_h1[2],_h1[3]};   \
    }                                                                           \
    const f32x4 _ci = {cjv, cjv, cjv, cjv};                                     \
    _Pragma("unroll") for (int _m = 0; _m < 4; ++_m)                            \
      ACC[_m] = __builtin_amdgcn_mfma_scale_f32_16x16x128_f8f6f4(               \
          a[_m][0], bf0, _ci, 0, 0, 0, 0x7F, 0, 0x7F);                          \
    _Pragma("unroll") for (int _m = 0; _m < 4; ++_m)                            \
      ACC[_m] = __builtin_amdgcn_mfma_scale_f32_16x16x128_f8f6f4(               \
          a[_m][1], bf1, ACC[_m], 0, 0, 0, 0x7F, 0, 0x7F);                      \
    __builtin_amdgcn_sched_barrier(0);                                          \
    if ((t_) + 2 < NT) STAGE((t_) + 2, h_);                                     \
  } while (0)

// ---- K2: barrier-free main loop (r20 structure). 8 waves = 2 row-groups x 4
//          col-strips; A converted fp32->negated-fp8 IN PROLOGUE (no XqN
//          buffer); xhalf computed in-block; cj prefetched a pair ahead;
//          last-block ticket folds in k_final.
__global__ __attribute__((amdgpu_flat_work_group_size(512, 512),
                          amdgpu_waves_per_eu(2, 2)))
void k_gemm(const float* __restrict__ X, const uint32_t* __restrict__ Yq,
            const float* __restrict__ cbuf, const float* __restrict__ psum,
            float* __restrict__ sum_accum, uint32_t* __restrict__ ticket,
            float* __restrict__ out)
{
  __shared__ __align__(16) char ldsB[XH_OFF + 512];

  const int brow = blockIdx.x * BM;
  const int tid  = threadIdx.x;
  const int wid  = tid >> 6;
  const int lane = tid & 63;
  const int rg    = wid >> 2;      // 0..1 -> rows rg*64
  const int strip = wid & 3;       // 0..3 -> cols strip*16 within each 64-tile
  const int c15 = lane & 15;
  const int w4  = lane >> 4;
  const int wbase = wid * 8192;    // private 8 KB dbuf
  const int cjo = (strip * 16 + c15) << 2;
  float* xhh = (float*)(ldsB + XH_OFF);

  // ---- prologue A: convert this block's X rows to negated-fp8 fragments
  // in registers; accumulate exact fp32 row sq-sums -> xhh[128] in LDS.
  int8v a[4][2];
  {
    #pragma unroll
    for (int m = 0; m < 4; ++m) {
      float ss = 0.f;
      #pragma unroll
      for (int kc = 0; kc < 2; ++kc) {
        const float* xp = X + (size_t)(brow + rg * 64 + m * 16 + c15) * DDIM
                          + kc * 128 + w4 * 32;
        uint32_t pk8[8];
        #pragma unroll
        for (int q = 0; q < 8; ++q) {
          float4 v = ((const float4*)xp)[q];
          ss += v.x*v.x + v.y*v.y + v.z*v.z + v.w*v.w;
          pk8[q] = pk4_fp8(v) ^ 0x80808080u;   // negate fp8 (sign bits)
        }
        a[m][kc] = (int8v){(int)pk8[0],(int)pk8[1],(int)pk8[2],(int)pk8[3],
                           (int)pk8[4],(int)pk8[5],(int)pk8[6],(int)pk8[7]};
      }
      // reduce sq-sum across the 4 w4-lane-groups holding this row
      ss += __shfl_xor(ss, 16);
      ss += __shfl_xor(ss, 32);
      if (w4 == 0) xhh[rg * 64 + m * 16 + c15] = 0.5f * ss;
    }
  }

  // per-lane stage sources for t=0: inst g covers cols 4g..4g+3 of the strip
  const char* srcG[4];
  #pragma unroll
  for (int g = 0; g < 4; ++g) {
    const int cin = 4 * g + (lane >> 4);              // in-strip col 0..15
    const int col = strip * 16 + cin;                 // in-tile col
    srcG[g] = (const char*)Yq + (size_t)col * 256 + (((lane & 15) ^ (cin & 15)) << 4);
  }

  // prologue: stage Cs (block-wide, 4 KB per wave) + tiles 0,1 into halves
  #pragma unroll
  for (int g = 0; g < 4; ++g)
    __builtin_amdgcn_global_load_lds(
        (const AS1 uint32_t*)((const char*)cbuf + wid * 4096 + g * 1024 + lane * 16),
        (AS3 uint32_t*)(ldsB + CS_OFF + wid * 4096 + g * 1024), 16, 0, 0);
  STAGE(0, 0);
  STAGE(1, 4096);
  asm volatile("s_waitcnt vmcnt(0)" ::: "memory");
  __builtin_amdgcn_s_barrier();    // Cs + xhh visible (only loop-side barrier)

  float cjP = *(const float*)(ldsB + CS_OFF + cjo);              // tile 0
  float cjQ = *(const float*)(ldsB + CS_OFF + (64 << 2) + cjo);  // tile 1

  f32x4 vmin[4];
  #pragma unroll
  for (int m = 0; m < 4; ++m)
    vmin[m] = (f32x4){3.4e38f, 3.4e38f, 3.4e38f, 3.4e38f};

  #pragma unroll 1
  for (int tt = 0; tt < NT; tt += 2) {
    f32x4 accP[4], accQ[4];
    ITERC(tt, 0, accP, cjP);
    // prefetch next pair's cj (consumed next iteration -> latency covered)
    float cjP2 = 0.f, cjQ2 = 0.f;
    if (tt + 2 < NT) {
      cjP2 = *(const float*)(ldsB + CS_OFF + (((tt + 2) * 64) << 2) + cjo);
      cjQ2 = *(const float*)(ldsB + CS_OFF + (((tt + 3) * 64) << 2) + cjo);
    }
    ITERC(tt + 1, 4096, accQ, cjQ);
    // pair fold: nested fmin -> v_min3_f32
    #pragma unroll
    for (int m = 0; m < 4; ++m)
      vmin[m] = vmin4(vmin4(vmin[m], accP[m]), accQ[m]);
    cjP = cjP2; cjQ = cjQ2;
  }

  // epilogue: per-wave min over its 16 cols; merge strips via LDS; sum rows;
  // last block (ticket) finalizes out. C/D: col = lane&15, row = (lane>>4)*4+reg
  float* Rw = (float*)(ldsB + RW_OFF);   // [4 strips][128 rows]
  #pragma unroll
  for (int m = 0; m < 4; ++m) {
    #pragma unroll
    for (int r = 0; r < 4; ++r) {
      float v = vmin[m][r];
      v = fminf(v, __shfl_xor(v, 1));
      v = fminf(v, __shfl_xor(v, 2));
      v = fminf(v, __shfl_xor(v, 4));
      v = fminf(v, __shfl_xor(v, 8));
      vmin[m][r] = v;
    }
    if (c15 < 4) {
      float vsel = vmin[m][0];
      vsel = (c15 == 1) ? vmin[m][1] : vsel;
      vsel = (c15 == 2) ? vmin[m][2] : vsel;
      vsel = (c15 == 3) ? vmin[m][3] : vsel;
      Rw[strip * 128 + rg * 64 + m * 16 + w4 * 4 + c15] = vsel;
    }
  }
  __syncthreads();

  float* part = (float*)(ldsB + PART_OFF);
  if (tid < BM) {
    float rm = fminf(fminf(Rw[tid], Rw[128 + tid]),
                     fminf(Rw[256 + tid], Rw[384 + tid]));
    float s = rm + xhh[tid];
    #pragma unroll
    for (int m = 32; m >= 1; m >>= 1) s += __shfl_xor(s, m);
    if (lane == 0) part[wid] = s;
  }
  __syncthreads();
  if (tid == 0) {
    atomicAdd(sum_accum, part[0] + part[1]);
    __threadfence();
    if (atomicAdd(ticket, 1u) == NWG - 1) {
      const float tot = *(volatile float*)sum_accum;
      out[0] = tot / (float)NROWS + psum[0];
    }
  }
}

extern "C" void kernel_launch(void* const* d_in, const int* in_sizes, int n_in,
                              void* d_out, int out_size, void* d_ws, size_t ws_size,
                              hipStream_t stream)
{
  const float* X   = (const float*)d_in[0];
  const float* Y   = (const float*)d_in[1];
  const float* psi = (const float*)d_in[2];
  float* out = (float*)d_out;

  char* ws = (char*)d_ws;
  uint32_t* Yq     = (uint32_t*)(ws);                                           // 2,097,152 B
  float* cbuf      = (float*)(ws + (size_t)MCOLS * DDIM);                       //    32,768 B
  float* psum      = (float*)((char*)cbuf + (size_t)MCOLS * 4);                 //         4 B
  float* sum_accum = (float*)((char*)psum + 16);                                //         4 B
  uint32_t* ticket = (uint32_t*)((char*)sum_accum + 16);                        //         4 B

  k_prepY<<<128, 256, 0, stream>>>(Y, psi, Yq, cbuf, psum, sum_accum, ticket);
  k_gemm <<<NWG, 512, 0, stream>>>(X, Yq, cbuf, psum, sum_accum, ticket, out);
}

// Round 22
// 80.137 us; speedup vs baseline: 1.2037x; 1.2037x over previous
//
#include <hip/hip_runtime.h>
#include <hip/hip_bf16.h>
#include <stdint.h>

#define NROWS 32768
#define MCOLS 8192
#define DDIM  256

#define BM 128            // rows per workgroup; block sweeps ALL cols
#define BN 64             // cols per iteration (4 strips x 16)
#define NT (MCOLS/BN)     // 128 iterations
#define NWG (NROWS/BM)    // 256 workgroups = 1 per CU

typedef __attribute__((ext_vector_type(8))) int   int8v;
typedef __attribute__((ext_vector_type(4))) int   int4v;
typedef __attribute__((ext_vector_type(4))) float f32x4;

#define AS1 __attribute__((address_space(1)))
#define AS3 __attribute__((address_space(3)))

// LDS map (bytes): [0,65536) = 8 waves x 8KB private dbuf B
//                  [65536,98304) = Cs (all 8192 cj)
//                  [98304,100352) = Rw[4][128] strip-min merge
#define CS_OFF 65536
#define RW_OFF 98304

// pack 4 f32 -> 4 fp8 e4m3 (OCP) via HW converter (RNE, saturating)
__device__ __forceinline__ uint32_t pk4_fp8(float4 v) {
  int p = __builtin_amdgcn_cvt_pk_fp8_f32(v.x, v.y, 0, false);
  p = __builtin_amdgcn_cvt_pk_fp8_f32(v.z, v.w, p, true);
  return (uint32_t)p;
}
__device__ __forceinline__ f32x4 vmin4(f32x4 x, f32x4 y) {
  f32x4 r;
  r[0] = fminf(x[0], y[0]); r[1] = fminf(x[1], y[1]);
  r[2] = fminf(x[2], y[2]); r[3] = fminf(x[3], y[3]);
  return r;
}

// ---- K1: prep. XqN = row-major fp8 NEGATED (acc C-init = cj -> cj - x.y);
//          Yq = row-major fp8; xhalf = 0.5||x||^2; cbuf = 0.5||y||^2 - psi;
//          block 0: psum = mean(psi), zero sum_accum + ticket.
__global__ void k_prep(const float* __restrict__ X, const float* __restrict__ Y,
                       const float* __restrict__ psi,
                       uint32_t* __restrict__ XqN, uint32_t* __restrict__ Yq,
                       float* __restrict__ xhalf, float* __restrict__ cbuf,
                       float* __restrict__ psum, float* __restrict__ sum_accum,
                       uint32_t* __restrict__ ticket)
{
  if (blockIdx.x == 0) {
    __shared__ float sh[4];
    float s = 0.f;
    for (int i = threadIdx.x; i < MCOLS; i += 256) s += psi[i];
    #pragma unroll
    for (int m = 32; m >= 1; m >>= 1) s += __shfl_xor(s, m);
    if ((threadIdx.x & 63) == 0) sh[threadIdx.x >> 6] = s;
    __syncthreads();
    if (threadIdx.x == 0) {
      psum[0] = (sh[0] + sh[1] + sh[2] + sh[3]) / (float)MCOLS;
      sum_accum[0] = 0.0f;
      ticket[0] = 0u;
    }
  }
  const int lane = threadIdx.x & 63;
  const int gw = (blockIdx.x * blockDim.x + threadIdx.x) >> 6;
  const int nw = (gridDim.x * blockDim.x) >> 6;
  for (int row = gw; row < NROWS + MCOLS; row += nw) {
    const bool isX = row < NROWS;
    const int r = isX ? row : row - NROWS;
    const float* src = isX ? (X + (size_t)row * DDIM) : (Y + (size_t)r * DDIM);
    float4 v = ((const float4*)src)[lane];
    const uint32_t pk = pk4_fp8(v);
    if (isX) XqN[(size_t)row * 64 + lane] = pk ^ 0x80808080u;   // negate fp8
    else     Yq[(size_t)r * 64 + lane] = pk;
    float s = v.x*v.x + v.y*v.y + v.z*v.z + v.w*v.w;
    #pragma unroll
    for (int m = 32; m >= 1; m >>= 1) s += __shfl_xor(s, m);
    if (lane == 0) {
      if (isX) xhalf[row] = 0.5f * s;
      else     cbuf[r] = 0.5f * s - psi[r];
    }
  }
}

// stage this wave's OWN 16-col strip of tile t_ (4 KB) into its private LDS
// half h_ (0/4096). XOR involution: LDS[c][q] = Yq[col][q ^ (c&15)]; dest
// linear (rule #21). srcG[g] precomputed per-lane for t=0; +t*16384 per tile.
#define STAGE(t_, h_) do {                                                      \
    _Pragma("unroll") for (int _g = 0; _g < 4; ++_g)                            \
      __builtin_amdgcn_global_load_lds(                                         \
          (const AS1 uint32_t*)(srcG[_g] + (size_t)(t_) * 16384),               \
          (AS3 uint32_t*)(ldsB + wbase + (h_) + _g * 1024), 16, 0, 0);          \
  } while (0)

// one body (r20 schedule): read own strip frags (4 b128) + cj; 8 MFMA with
// C-init = cj into ACC (NO vmin fold here); stage t_+2 into the half consumed.
#define ITERC(t_, h_, ACC) do {                                                 \
    asm volatile("s_waitcnt vmcnt(4)" ::: "memory");                            \
    int8v bf0, bf1;                                                             \
    {                                                                           \
      const char* _b = ldsB + wbase + (h_) + c15 * 256;                         \
      const int4v _l0 = *(const int4v*)(_b + (((w4 * 2 + 0) ^ c15) << 4));      \
      const int4v _h0 = *(const int4v*)(_b + (((w4 * 2 + 1) ^ c15) << 4));      \
      const int4v _l1 = *(const int4v*)(_b + (((8 + w4 * 2 + 0) ^ c15) << 4));  \
      const int4v _h1 = *(const int4v*)(_b + (((8 + w4 * 2 + 1) ^ c15) << 4));  \
      bf0 = (int8v){_l0[0],_l0[1],_l0[2],_l0[3],_h0[0],_h0[1],_h0[2],_h0[3]};   \
      bf1 = (int8v){_l1[0],_l1[1],_l1[2],_l1[3],_h1[0],_h1[1],_h1[2],_h1[3]};   \
    }                                                                           \
    const float cj = *(const float*)(ldsB + CS_OFF + (((t_) * 64) << 2) + cjo); \
    const f32x4 _ci = {cj, cj, cj, cj};                                         \
    _Pragma("unroll") for (int _m = 0; _m < 4; ++_m)                            \
      ACC[_m] = __builtin_amdgcn_mfma_scale_f32_16x16x128_f8f6f4(               \
          a[_m][0], bf0, _ci, 0, 0, 0, 0x7F, 0, 0x7F);                          \
    _Pragma("unroll") for (int _m = 0; _m < 4; ++_m)                            \
      ACC[_m] = __builtin_amdgcn_mfma_scale_f32_16x16x128_f8f6f4(               \
          a[_m][1], bf1, ACC[_m], 0, 0, 0, 0x7F, 0, 0x7F);                      \
    __builtin_amdgcn_sched_barrier(0);                                          \
    if ((t_) + 2 < NT) STAGE((t_) + 2, h_);                                     \
  } while (0)

// ---- K2: barrier-free main loop (r20 structure). 8 waves = 2 row-groups x 4
//          col-strips; A (64 rows) in regs; each wave stages its own strip
//          into private dbuf LDS; counted vmcnt only; pair-folded min3 vmin;
//          last block (ticket) finalizes out.
__global__ __attribute__((amdgpu_flat_work_group_size(512, 512),
                          amdgpu_waves_per_eu(2, 2)))
void k_gemm(const uint32_t* __restrict__ XqN, const uint32_t* __restrict__ Yq,
            const float* __restrict__ cbuf, const float* __restrict__ xhalf,
            const float* __restrict__ psum, float* __restrict__ sum_accum,
            uint32_t* __restrict__ ticket, float* __restrict__ out)
{
  __shared__ __align__(16) char ldsB[100352 + 8];

  const int brow = blockIdx.x * BM;
  const int tid  = threadIdx.x;
  const int wid  = tid >> 6;
  const int lane = tid & 63;
  const int rg    = wid >> 2;      // 0..1 -> rows rg*64
  const int strip = wid & 3;       // 0..3 -> cols strip*16 within each 64-tile
  const int c15 = lane & 15;
  const int w4  = lane >> 4;
  const int wbase = wid * 8192;    // private 8 KB dbuf
  const int cjo = (strip * 16 + c15) << 2;

  // A fragments (negated fp8): rows brow + rg*64 + m*16 + c15; bytes kc*128+w4*32
  int8v a[4][2];
  {
    const char* aBase = (const char*)XqN + ((size_t)(brow + rg * 64 + c15) << 8) + w4 * 32;
    #pragma unroll
    for (int m = 0; m < 4; ++m)
      #pragma unroll
      for (int kc = 0; kc < 2; ++kc)
        a[m][kc] = *(const int8v*)(aBase + m * 4096 + kc * 128);
  }

  // per-lane stage sources for t=0: inst g covers cols 4g..4g+3 of the strip
  const char* srcG[4];
  #pragma unroll
  for (int g = 0; g < 4; ++g) {
    const int cin = 4 * g + (lane >> 4);              // in-strip col 0..15
    const int col = strip * 16 + cin;                 // in-tile col
    srcG[g] = (const char*)Yq + (size_t)col * 256 + (((lane & 15) ^ (cin & 15)) << 4);
  }

  // prologue: stage Cs (block-wide, 4 KB per wave) + tiles 0,1 into halves
  #pragma unroll
  for (int g = 0; g < 4; ++g)
    __builtin_amdgcn_global_load_lds(
        (const AS1 uint32_t*)((const char*)cbuf + wid * 4096 + g * 1024 + lane * 16),
        (AS3 uint32_t*)(ldsB + CS_OFF + wid * 4096 + g * 1024), 16, 0, 0);
  STAGE(0, 0);
  STAGE(1, 4096);
  asm volatile("s_waitcnt vmcnt(0)" ::: "memory");
  __builtin_amdgcn_s_barrier();    // Cs visible to all waves (only loop-side barrier)

  f32x4 vmin[4];
  #pragma unroll
  for (int m = 0; m < 4; ++m)
    vmin[m] = (f32x4){3.4e38f, 3.4e38f, 3.4e38f, 3.4e38f};

  #pragma unroll 1
  for (int tt = 0; tt < NT; tt += 2) {
    f32x4 accP[4], accQ[4];
    ITERC(tt,     0,    accP);
    ITERC(tt + 1, 4096, accQ);
    // pair fold: nested fmin -> v_min3_f32 (16 min3 per pair vs 32 fmin)
    #pragma unroll
    for (int m = 0; m < 4; ++m)
      vmin[m] = vmin4(vmin4(vmin[m], accP[m]), accQ[m]);
  }

  // epilogue: per-wave min over its 16 cols; merge strips via LDS; sum rows;
  // last block finalizes. C/D layout: col = lane&15, row = (lane>>4)*4 + reg
  float* Rw = (float*)(ldsB + RW_OFF);   // [4 strips][128 rows]
  #pragma unroll
  for (int m = 0; m < 4; ++m) {
    #pragma unroll
    for (int r = 0; r < 4; ++r) {
      float v = vmin[m][r];
      v = fminf(v, __shfl_xor(v, 1));
      v = fminf(v, __shfl_xor(v, 2));
      v = fminf(v, __shfl_xor(v, 4));
      v = fminf(v, __shfl_xor(v, 8));
      vmin[m][r] = v;
    }
    if (c15 < 4) {
      float vsel = vmin[m][0];
      vsel = (c15 == 1) ? vmin[m][1] : vsel;
      vsel = (c15 == 2) ? vmin[m][2] : vsel;
      vsel = (c15 == 3) ? vmin[m][3] : vsel;
      Rw[strip * 128 + rg * 64 + m * 16 + w4 * 4 + c15] = vsel;
    }
  }
  __syncthreads();

  float* part = (float*)(ldsB + 100352);
  if (tid < BM) {
    float rm = fminf(fminf(Rw[tid], Rw[128 + tid]),
                     fminf(Rw[256 + tid], Rw[384 + tid]));
    float s = rm + xhalf[brow + tid];
    #pragma unroll
    for (int m = 32; m >= 1; m >>= 1) s += __shfl_xor(s, m);
    if (lane == 0) part[wid] = s;
  }
  __syncthreads();
  if (tid == 0) {
    atomicAdd(sum_accum, part[0] + part[1]);
    __threadfence();
    if (atomicAdd(ticket, 1u) == NWG - 1) {
      const float tot = *(volatile float*)sum_accum;
      out[0] = tot / (float)NROWS + psum[0];
    }
  }
}

extern "C" void kernel_launch(void* const* d_in, const int* in_sizes, int n_in,
                              void* d_out, int out_size, void* d_ws, size_t ws_size,
                              hipStream_t stream)
{
  const float* X   = (const float*)d_in[0];
  const float* Y   = (const float*)d_in[1];
  const float* psi = (const float*)d_in[2];
  float* out = (float*)d_out;

  char* ws = (char*)d_ws;
  uint32_t* XqN    = (uint32_t*)(ws);                                           // 8,388,608 B
  uint32_t* Yq     = (uint32_t*)(ws + (size_t)NROWS * DDIM);                    // 2,097,152 B
  float* cbuf      = (float*)(ws + (size_t)(NROWS + MCOLS) * DDIM);             //    32,768 B
  float* xhalf     = (float*)((char*)cbuf + (size_t)MCOLS * 4);                 //   131,072 B
  float* psum      = (float*)((char*)xhalf + (size_t)NROWS * 4);                //         4 B
  float* sum_accum = (float*)((char*)psum + 16);                                //         4 B
  uint32_t* ticket = (uint32_t*)((char*)sum_accum + 16);                        //         4 B

  k_prep<<<2048, 256, 0, stream>>>(X, Y, psi, XqN, Yq, xhalf, cbuf,
                                   psum, sum_accum, ticket);
  k_gemm<<<NWG, 512, 0, stream>>>(XqN, Yq, cbuf, xhalf, psum,
                                  sum_accum, ticket, out);
}

// Round 23
// 79.314 us; speedup vs baseline: 1.2162x; 1.0104x over previous
//
#include <hip/hip_runtime.h>
#include <hip/hip_bf16.h>
#include <stdint.h>

#define NROWS 32768
#define MCOLS 8192
#define DDIM  256

#define BM 128            // rows per workgroup; block sweeps ALL cols
#define BN 128            // cols per tile (4 strips x 32)
#define NT (MCOLS/BN)     // 64 tiles
#define NWG (NROWS/BM)    // 256 workgroups = 1 per CU

typedef __attribute__((ext_vector_type(8))) int   int8v;
typedef __attribute__((ext_vector_type(4))) int   int4v;
typedef __attribute__((ext_vector_type(4))) float f32x4;

#define AS1 __attribute__((address_space(1)))
#define AS3 __attribute__((address_space(3)))

// LDS map (bytes): [0,131072) = 8 waves x 16KB private dbuf B (2 x 8KB halves)
//                  [131072,133120) = Rw[4][128] strip-min merge
//                  [133120,133136) = part
#define RW_OFF   131072
#define PART_OFF 133120

// pack 4 f32 -> 4 fp8 e4m3 (OCP) via HW converter (RNE, saturating)
__device__ __forceinline__ uint32_t pk4_fp8(float4 v) {
  int p = __builtin_amdgcn_cvt_pk_fp8_f32(v.x, v.y, 0, false);
  p = __builtin_amdgcn_cvt_pk_fp8_f32(v.z, v.w, p, true);
  return (uint32_t)p;
}
// order-preserving float -> uint key helpers not needed (single-block rows)
__device__ __forceinline__ f32x4 vmin4(f32x4 x, f32x4 y) {
  f32x4 r;
  r[0] = fminf(x[0], y[0]); r[1] = fminf(x[1], y[1]);
  r[2] = fminf(x[2], y[2]); r[3] = fminf(x[3], y[3]);
  return r;
}

// ---- K1: prep (r20 verbatim). XqN = row-major fp8 NEGATED; Yq = row-major
//          fp8; xhalf = 0.5||x||^2; cbuf = 0.5||y||^2 - psi; zero accum.
__global__ void k_prep(const float* __restrict__ X, const float* __restrict__ Y,
                       const float* __restrict__ psi,
                       uint32_t* __restrict__ XqN, uint32_t* __restrict__ Yq,
                       float* __restrict__ xhalf, float* __restrict__ cbuf,
                       float* __restrict__ sum_accum)
{
  const int lane = threadIdx.x & 63;
  const int gw = (blockIdx.x * blockDim.x + threadIdx.x) >> 6;
  const int nw = (gridDim.x * blockDim.x) >> 6;
  for (int row = gw; row < NROWS + MCOLS; row += nw) {
    const bool isX = row < NROWS;
    const int r = isX ? row : row - NROWS;
    const float* src = isX ? (X + (size_t)row * DDIM) : (Y + (size_t)r * DDIM);
    float4 v = ((const float4*)src)[lane];
    const uint32_t pk = pk4_fp8(v);
    if (isX) XqN[(size_t)row * 64 + lane] = pk ^ 0x80808080u;   // negate fp8
    else     Yq[(size_t)r * 64 + lane] = pk;
    float s = v.x*v.x + v.y*v.y + v.z*v.z + v.w*v.w;
    #pragma unroll
    for (int m = 32; m >= 1; m >>= 1) s += __shfl_xor(s, m);
    if (lane == 0) {
      if (isX) xhalf[row] = 0.5f * s;
      else     cbuf[r] = 0.5f * s - psi[r];
    }
  }
  if (blockIdx.x == 0 && threadIdx.x == 0) sum_accum[0] = 0.0f;
}

// stage this wave's OWN 32-col strip of tile t_ (8 KB) into its private LDS
// half h_ (0/8192). XOR involution: LDS[cin][q] = Yq[col][q ^ (cin&15)];
// dest linear (rule #21). srcG[g] per-lane for t=0; +t*32768 per tile.
#define STAGE(t_, h_) do {                                                      \
    _Pragma("unroll") for (int _g = 0; _g < 8; ++_g)                            \
      __builtin_amdgcn_global_load_lds(                                         \
          (const AS1 uint32_t*)(srcG[_g] + (size_t)(t_) * 32768),               \
          (AS3 uint32_t*)(ldsB + wbase + (h_) + _g * 1024), 16, 0, 0);          \
  } while (0)

// one body: wait VM (steady vmcnt(10): own tile's cj+stage complete, next
// tile's 10 ops stay in flight); read 8 swizzled b128 frags (2 col-groups x
// 2 kc); 16 MFMA (8 chains, C-init = cj); issue cj(t_+2) + STAGE(t_+2); fold.
#define ITERC(t_, h_, VM, ISSUE) do {                                           \
    asm volatile("s_waitcnt " VM ::: "memory");                                 \
    int8v bf0[2], bf1[2];                                                       \
    {                                                                           \
      const char* _b = ldsB + wbase + (h_) + c15 * 256;                         \
      _Pragma("unroll") for (int _kc = 0; _kc < 2; ++_kc) {                     \
        const int4v _l0 = *(const int4v*)(_b + (((_kc*8 + w4*2 + 0) ^ c15) << 4)); \
        const int4v _h0 = *(const int4v*)(_b + (((_kc*8 + w4*2 + 1) ^ c15) << 4)); \
        const int4v _l1 = *(const int4v*)(_b + 4096 + (((_kc*8 + w4*2 + 0) ^ c15) << 4)); \
        const int4v _h1 = *(const int4v*)(_b + 4096 + (((_kc*8 + w4*2 + 1) ^ c15) << 4)); \
        bf0[_kc] = (int8v){_l0[0],_l0[1],_l0[2],_l0[3],_h0[0],_h0[1],_h0[2],_h0[3]}; \
        bf1[_kc] = (int8v){_l1[0],_l1[1],_l1[2],_l1[3],_h1[0],_h1[1],_h1[2],_h1[3]}; \
      }                                                                         \
    }                                                                           \
    const f32x4 _c0 = {cj0, cj0, cj0, cj0};                                     \
    const f32x4 _c1 = {cj1, cj1, cj1, cj1};                                     \
    f32x4 acc0[4], acc1[4];                                                     \
    _Pragma("unroll") for (int _m = 0; _m < 4; ++_m) {                          \
      acc0[_m] = __builtin_amdgcn_mfma_scale_f32_16x16x128_f8f6f4(              \
          a[_m][0], bf0[0], _c0, 0, 0, 0, 0x7F, 0, 0x7F);                       \
      acc1[_m] = __builtin_amdgcn_mfma_scale_f32_16x16x128_f8f6f4(              \
          a[_m][0], bf1[0], _c1, 0, 0, 0, 0x7F, 0, 0x7F);                       \
    }                                                                           \
    _Pragma("unroll") for (int _m = 0; _m < 4; ++_m) {                          \
      acc0[_m] = __builtin_amdgcn_mfma_scale_f32_16x16x128_f8f6f4(              \
          a[_m][1], bf0[1], acc0[_m], 0, 0, 0, 0x7F, 0, 0x7F);                  \
      acc1[_m] = __builtin_amdgcn_mfma_scale_f32_16x16x128_f8f6f4(              \
          a[_m][1], bf1[1], acc1[_m], 0, 0, 0, 0x7F, 0, 0x7F);                  \
    }                                                                           \
    __builtin_amdgcn_sched_barrier(0);                                          \
    if (ISSUE) {                                                                \
      cj0 = cjPtr[((t_) + 2) * BN];                                             \
      cj1 = cjPtr[((t_) + 2) * BN + 16];                                        \
      STAGE((t_) + 2, h_);                                                      \
    }                                                                           \
    _Pragma("unroll") for (int _m = 0; _m < 4; ++_m)                            \
      vmin[_m] = vmin4(vmin4(vmin[_m], acc0[_m]), acc1[_m]);                    \
  } while (0)

// ---- K2: barrier-free main loop, BN=128. 8 waves = 2 row-groups x 4
//          col-strips (32 cols each); A (64 rows) in regs; 16KB private
//          dbuf LDS per wave; cj from global, issued 2 tiles ahead.
__global__ __attribute__((amdgpu_flat_work_group_size(512, 512),
                          amdgpu_waves_per_eu(2, 2)))
void k_gemm(const uint32_t* __restrict__ XqN, const uint32_t* __restrict__ Yq,
            const float* __restrict__ cbuf, const float* __restrict__ xhalf,
            float* __restrict__ sum_accum)
{
  __shared__ __align__(16) char ldsB[PART_OFF + 16];

  const int brow = blockIdx.x * BM;
  const int tid  = threadIdx.x;
  const int wid  = tid >> 6;
  const int lane = tid & 63;
  const int rg    = wid >> 2;      // 0..1 -> rows rg*64
  const int strip = wid & 3;       // 0..3 -> cols strip*32 within each 128-tile
  const int c15 = lane & 15;
  const int w4  = lane >> 4;
  const int wbase = wid * 16384;   // private 16 KB dbuf

  // A fragments (negated fp8): rows brow + rg*64 + m*16 + c15; bytes kc*128+w4*32
  int8v a[4][2];
  {
    const char* aBase = (const char*)XqN + ((size_t)(brow + rg * 64 + c15) << 8) + w4 * 32;
    #pragma unroll
    for (int m = 0; m < 4; ++m)
      #pragma unroll
      for (int kc = 0; kc < 2; ++kc)
        a[m][kc] = *(const int8v*)(aBase + m * 4096 + kc * 128);
  }

  // per-lane stage sources for t=0: inst g covers strip cols 4g..4g+3
  const char* srcG[8];
  #pragma unroll
  for (int g = 0; g < 8; ++g) {
    const int cin = 4 * g + (lane >> 4);              // in-strip col 0..31
    const int col = strip * 32 + cin;                 // in-tile col
    srcG[g] = (const char*)Yq + (size_t)col * 256 + (((lane & 15) ^ (cin & 15)) << 4);
  }
  const float* cjPtr = cbuf + strip * 32 + c15;

  // prologue: issue [cj(0), stage(0)] then [cj(1), stage(1)] -> 20 ops;
  // body 0's vmcnt(10) drains exactly cj(0)+stage(0).
  float cj0 = cjPtr[0], cj1 = cjPtr[16];
  STAGE(0, 0);
  float cjN0 = cjPtr[BN], cjN1 = cjPtr[BN + 16];
  STAGE(1, 8192);

  f32x4 vmin[4];
  #pragma unroll
  for (int m = 0; m < 4; ++m)
    vmin[m] = (f32x4){3.4e38f, 3.4e38f, 3.4e38f, 3.4e38f};

  // register rotation: even bodies use (cj0,cj1) and reload them for t+2;
  // odd bodies use (cjN0,cjN1) likewise.
  #pragma unroll 1
  for (int tt = 0; tt < NT - 2; tt += 2) {
    ITERC(tt, 0, "vmcnt(10)", 1);
    { float t0 = cj0, t1 = cj1; cj0 = cjN0; cj1 = cjN1; cjN0 = t0; cjN1 = t1; }
    ITERC(tt + 1, 8192, "vmcnt(10)", 1);
    { float t0 = cj0, t1 = cj1; cj0 = cjN0; cj1 = cjN1; cjN0 = t0; cjN1 = t1; }
  }
  // peeled tail: bodies NT-2 (no issue) and NT-1 (final drain)
  ITERC(NT - 2, 0, "vmcnt(10)", 0);
  { float t0 = cj0, t1 = cj1; cj0 = cjN0; cj1 = cjN1; cjN0 = t0; cjN1 = t1; }
  ITERC(NT - 1, 8192, "vmcnt(0)", 0);

  // epilogue: per-wave min over its 32 cols (both 16-col groups folded in
  // vmin); shfl-reduce over 16 lanes; merge strips via LDS; sum rows.
  // C/D layout: col = lane&15, row = (lane>>4)*4 + reg
  float* Rw = (float*)(ldsB + RW_OFF);   // [4 strips][128 rows]
  #pragma unroll
  for (int m = 0; m < 4; ++m) {
    #pragma unroll
    for (int r = 0; r < 4; ++r) {
      float v = vmin[m][r];
      v = fminf(v, __shfl_xor(v, 1));
      v = fminf(v, __shfl_xor(v, 2));
      v = fminf(v, __shfl_xor(v, 4));
      v = fminf(v, __shfl_xor(v, 8));
      vmin[m][r] = v;
    }
    if (c15 < 4) {
      float vsel = vmin[m][0];
      vsel = (c15 == 1) ? vmin[m][1] : vsel;
      vsel = (c15 == 2) ? vmin[m][2] : vsel;
      vsel = (c15 == 3) ? vmin[m][3] : vsel;
      Rw[strip * 128 + rg * 64 + m * 16 + w4 * 4 + c15] = vsel;
    }
  }
  __syncthreads();

  float* part = (float*)(ldsB + PART_OFF);
  if (tid < BM) {
    float rm = fminf(fminf(Rw[tid], Rw[128 + tid]),
                     fminf(Rw[256 + tid], Rw[384 + tid]));
    float s = rm + xhalf[brow + tid];
    #pragma unroll
    for (int m = 32; m >= 1; m >>= 1) s += __shfl_xor(s, m);
    if (lane == 0) part[wid] = s;
  }
  __syncthreads();
  if (tid == 0) atomicAdd(sum_accum, part[0] + part[1]);
}

// ---- K3: out = sum/N + mean(psi)
__global__ void k_final(const float* __restrict__ psi, const float* __restrict__ sum_accum,
                        float* __restrict__ out)
{
  __shared__ float sh[4];
  float s = 0.f;
  for (int i = threadIdx.x; i < MCOLS; i += 256) s += psi[i];
  #pragma unroll
  for (int m = 32; m >= 1; m >>= 1) s += __shfl_xor(s, m);
  const int wid = threadIdx.x >> 6, lane = threadIdx.x & 63;
  if (lane == 0) sh[wid] = s;
  __syncthreads();
  if (threadIdx.x == 0)
    out[0] = sum_accum[0] / (float)NROWS + (sh[0] + sh[1] + sh[2] + sh[3]) / (float)MCOLS;
}

extern "C" void kernel_launch(void* const* d_in, const int* in_sizes, int n_in,
                              void* d_out, int out_size, void* d_ws, size_t ws_size,
                              hipStream_t stream)
{
  const float* X   = (const float*)d_in[0];
  const float* Y   = (const float*)d_in[1];
  const float* psi = (const float*)d_in[2];
  float* out = (float*)d_out;

  char* ws = (char*)d_ws;
  uint32_t* XqN    = (uint32_t*)(ws);                                           // 8,388,608 B
  uint32_t* Yq     = (uint32_t*)(ws + (size_t)NROWS * DDIM);                    // 2,097,152 B
  float* cbuf      = (float*)(ws + (size_t)(NROWS + MCOLS) * DDIM);             //    32,768 B
  float* xhalf     = (float*)((char*)cbuf + (size_t)MCOLS * 4);                 //   131,072 B
  float* sum_accum = (float*)((char*)xhalf + (size_t)NROWS * 4);                //         4 B

  k_prep <<<2048, 256, 0, stream>>>(X, Y, psi, XqN, Yq, xhalf, cbuf, sum_accum);
  k_gemm <<<NWG, 512, 0, stream>>>(XqN, Yq, cbuf, xhalf, sum_accum);
  k_final<<<1, 256, 0, stream>>>(psi, sum_accum, out);
}

// Round 24
// 77.827 us; speedup vs baseline: 1.2395x; 1.0191x over previous
//
#include <hip/hip_runtime.h>
#include <hip/hip_bf16.h>
#include <stdint.h>

#define NROWS 32768
#define MCOLS 8192
#define DDIM  256

#define BM 128            // rows per workgroup; block sweeps ALL cols
#define BN 64             // cols per iteration (4 strips x 16)
#define NT (MCOLS/BN)     // 128 iterations
#define NWG (NROWS/BM)    // 256 workgroups = 1 per CU

typedef __attribute__((ext_vector_type(8))) int   int8v;
typedef __attribute__((ext_vector_type(4))) int   int4v;
typedef __attribute__((ext_vector_type(4))) float f32x4;

#define AS1 __attribute__((address_space(1)))
#define AS3 __attribute__((address_space(3)))

// LDS map (bytes): [0,65536) = 8 waves x 8KB private dbuf B
//                  [65536,98304) = Cs (all 8192 cj)
//                  [98304,100352) = Rw[4][128] strip-min merge
#define CS_OFF 65536
#define RW_OFF 98304

// pack 4 f32 -> 4 fp8 e4m3 (OCP) via HW converter (RNE, saturating)
__device__ __forceinline__ uint32_t pk4_fp8(float4 v) {
  int p = __builtin_amdgcn_cvt_pk_fp8_f32(v.x, v.y, 0, false);
  p = __builtin_amdgcn_cvt_pk_fp8_f32(v.z, v.w, p, true);
  return (uint32_t)p;
}
__device__ __forceinline__ f32x4 vmin4(f32x4 x, f32x4 y) {
  f32x4 r;
  r[0] = fminf(x[0], y[0]); r[1] = fminf(x[1], y[1]);
  r[2] = fminf(x[2], y[2]); r[3] = fminf(x[3], y[3]);
  return r;
}

// ---- K1: prep. XqN = row-major fp8 NEGATED (acc C-init = cj -> cj - x.y);
//          Yq = row-major fp8; xhalf = 0.5||x||^2; cbuf = 0.5||y||^2 - psi.
__global__ void k_prep(const float* __restrict__ X, const float* __restrict__ Y,
                       const float* __restrict__ psi,
                       uint32_t* __restrict__ XqN, uint32_t* __restrict__ Yq,
                       float* __restrict__ xhalf, float* __restrict__ cbuf,
                       float* __restrict__ sum_accum)
{
  const int lane = threadIdx.x & 63;
  const int gw = (blockIdx.x * blockDim.x + threadIdx.x) >> 6;
  const int nw = (gridDim.x * blockDim.x) >> 6;
  for (int row = gw; row < NROWS + MCOLS; row += nw) {
    const bool isX = row < NROWS;
    const int r = isX ? row : row - NROWS;
    const float* src = isX ? (X + (size_t)row * DDIM) : (Y + (size_t)r * DDIM);
    float4 v = ((const float4*)src)[lane];
    const uint32_t pk = pk4_fp8(v);
    if (isX) XqN[(size_t)row * 64 + lane] = pk ^ 0x80808080u;   // negate fp8
    else     Yq[(size_t)r * 64 + lane] = pk;
    float s = v.x*v.x + v.y*v.y + v.z*v.z + v.w*v.w;
    #pragma unroll
    for (int m = 32; m >= 1; m >>= 1) s += __shfl_xor(s, m);
    if (lane == 0) {
      if (isX) xhalf[row] = 0.5f * s;
      else     cbuf[r] = 0.5f * s - psi[r];
    }
  }
  if (blockIdx.x == 0 && threadIdx.x == 0) sum_accum[0] = 0.0f;
}

// stage this wave's OWN 16-col strip of tile t_ (4 KB) into its private LDS
// half h_ (0/4096). XOR involution: LDS[c][q] = Yq[col][q ^ (c&15)]; dest
// linear (rule #21). srcG[g] precomputed per-lane for t=0; +t*16384 per tile.
#define STAGE(t_, h_) do {                                                      \
    _Pragma("unroll") for (int _g = 0; _g < 4; ++_g)                            \
      __builtin_amdgcn_global_load_lds(                                         \
          (const AS1 uint32_t*)(srcG[_g] + (size_t)(t_) * 16384),               \
          (AS3 uint32_t*)(ldsB + wbase + (h_) + _g * 1024), 16, 0, 0);          \
  } while (0)

// one body (r12 schedule): read own strip frags (4 b128) + cj; 8 MFMA with
// C-init = cj into ACC (NO vmin fold here); stage t_+2 into the half consumed.
#define ITERC(t_, h_, ACC) do {                                                 \
    asm volatile("s_waitcnt vmcnt(4)" ::: "memory");                            \
    int8v bf0, bf1;                                                             \
    {                                                                           \
      const char* _b = ldsB + wbase + (h_) + c15 * 256;                         \
      const int4v _l0 = *(const int4v*)(_b + (((w4 * 2 + 0) ^ c15) << 4));      \
      const int4v _h0 = *(const int4v*)(_b + (((w4 * 2 + 1) ^ c15) << 4));      \
      const int4v _l1 = *(const int4v*)(_b + (((8 + w4 * 2 + 0) ^ c15) << 4));  \
      const int4v _h1 = *(const int4v*)(_b + (((8 + w4 * 2 + 1) ^ c15) << 4));  \
      bf0 = (int8v){_l0[0],_l0[1],_l0[2],_l0[3],_h0[0],_h0[1],_h0[2],_h0[3]};   \
      bf1 = (int8v){_l1[0],_l1[1],_l1[2],_l1[3],_h1[0],_h1[1],_h1[2],_h1[3]};   \
    }                                                                           \
    const float cj = *(const float*)(ldsB + CS_OFF + (((t_) * 64) << 2) + cjo); \
    const f32x4 _ci = {cj, cj, cj, cj};                                         \
    _Pragma("unroll") for (int _m = 0; _m < 4; ++_m)                            \
      ACC[_m] = __builtin_amdgcn_mfma_scale_f32_16x16x128_f8f6f4(               \
          a[_m][0], bf0, _ci, 0, 0, 0, 0x7F, 0, 0x7F);                          \
    _Pragma("unroll") for (int _m = 0; _m < 4; ++_m)                            \
      ACC[_m] = __builtin_amdgcn_mfma_scale_f32_16x16x128_f8f6f4(               \
          a[_m][1], bf1, ACC[_m], 0, 0, 0, 0x7F, 0, 0x7F);                      \
    __builtin_amdgcn_sched_barrier(0);                                          \
    if ((t_) + 2 < NT) STAGE((t_) + 2, h_);                                     \
  } while (0)

// ---- K2: barrier-free main loop (r12/r20 structure). 8 waves = 2 row-groups
//          x 4 col-strips; A (64 rows) in regs; each wave stages its own strip
//          into private dbuf LDS; counted vmcnt only; pair-folded min3 vmin.
__global__ __attribute__((amdgpu_flat_work_group_size(512, 512),
                          amdgpu_waves_per_eu(2, 2)))
void k_gemm(const uint32_t* __restrict__ XqN, const uint32_t* __restrict__ Yq,
            const float* __restrict__ cbuf, const float* __restrict__ xhalf,
            float* __restrict__ sum_accum)
{
  __shared__ __align__(16) char ldsB[100352 + 8];

  const int brow = blockIdx.x * BM;
  const int tid  = threadIdx.x;
  const int wid  = tid >> 6;
  const int lane = tid & 63;
  const int rg    = wid >> 2;      // 0..1 -> rows rg*64
  const int strip = wid & 3;       // 0..3 -> cols strip*16 within each 64-tile
  const int c15 = lane & 15;
  const int w4  = lane >> 4;
  const int wbase = wid * 8192;    // private 8 KB dbuf
  const int cjo = (strip * 16 + c15) << 2;

  // A fragments (negated fp8): rows brow + rg*64 + m*16 + c15; bytes kc*128+w4*32
  int8v a[4][2];
  {
    const char* aBase = (const char*)XqN + ((size_t)(brow + rg * 64 + c15) << 8) + w4 * 32;
    #pragma unroll
    for (int m = 0; m < 4; ++m)
      #pragma unroll
      for (int kc = 0; kc < 2; ++kc)
        a[m][kc] = *(const int8v*)(aBase + m * 4096 + kc * 128);
  }

  // per-lane stage sources for t=0: inst g covers cols 4g..4g+3 of the strip
  const char* srcG[4];
  #pragma unroll
  for (int g = 0; g < 4; ++g) {
    const int cin = 4 * g + (lane >> 4);              // in-strip col 0..15
    const int col = strip * 16 + cin;                 // in-tile col
    srcG[g] = (const char*)Yq + (size_t)col * 256 + (((lane & 15) ^ (cin & 15)) << 4);
  }

  // prologue: stage Cs (block-wide, 4 KB per wave) + tiles 0,1 into halves
  #pragma unroll
  for (int g = 0; g < 4; ++g)
    __builtin_amdgcn_global_load_lds(
        (const AS1 uint32_t*)((const char*)cbuf + wid * 4096 + g * 1024 + lane * 16),
        (AS3 uint32_t*)(ldsB + CS_OFF + wid * 4096 + g * 1024), 16, 0, 0);
  STAGE(0, 0);
  STAGE(1, 4096);
  asm volatile("s_waitcnt vmcnt(0)" ::: "memory");
  __builtin_amdgcn_s_barrier();    // Cs visible to all waves (only loop-side barrier)

  f32x4 vmin[4];
  #pragma unroll
  for (int m = 0; m < 4; ++m)
    vmin[m] = (f32x4){3.4e38f, 3.4e38f, 3.4e38f, 3.4e38f};

  #pragma unroll 1
  for (int tt = 0; tt < NT; tt += 2) {
    f32x4 accP[4], accQ[4];
    ITERC(tt,     0,    accP);
    ITERC(tt + 1, 4096, accQ);
    // pair fold: nested fmin -> v_min3_f32 (16 min3 per pair vs 32 fmin)
    #pragma unroll
    for (int m = 0; m < 4; ++m)
      vmin[m] = vmin4(vmin4(vmin[m], accP[m]), accQ[m]);
  }

  // epilogue: per-wave min over its 16 cols; merge strips via LDS; sum rows.
  // C/D layout: col = lane&15, row = (lane>>4)*4 + reg
  float* Rw = (float*)(ldsB + RW_OFF);   // [4 strips][128 rows]
  #pragma unroll
  for (int m = 0; m < 4; ++m) {
    #pragma unroll
    for (int r = 0; r < 4; ++r) {
      float v = vmin[m][r];
      v = fminf(v, __shfl_xor(v, 1));
      v = fminf(v, __shfl_xor(v, 2));
      v = fminf(v, __shfl_xor(v, 4));
      v = fminf(v, __shfl_xor(v, 8));
      vmin[m][r] = v;
    }
    if (c15 < 4) {
      float vsel = vmin[m][0];
      vsel = (c15 == 1) ? vmin[m][1] : vsel;
      vsel = (c15 == 2) ? vmin[m][2] : vsel;
      vsel = (c15 == 3) ? vmin[m][3] : vsel;
      Rw[strip * 128 + rg * 64 + m * 16 + w4 * 4 + c15] = vsel;
    }
  }
  __syncthreads();

  float* part = (float*)(ldsB + 100352);
  if (tid < BM) {
    float rm = fminf(fminf(Rw[tid], Rw[128 + tid]),
                     fminf(Rw[256 + tid], Rw[384 + tid]));
    float s = rm + xhalf[brow + tid];
    #pragma unroll
    for (int m = 32; m >= 1; m >>= 1) s += __shfl_xor(s, m);
    if (lane == 0) part[wid] = s;
  }
  __syncthreads();
  if (tid == 0) atomicAdd(sum_accum, part[0] + part[1]);
}

// ---- K3: out = sum/N + mean(psi)
__global__ void k_final(const float* __restrict__ psi, const float* __restrict__ sum_accum,
                        float* __restrict__ out)
{
  __shared__ float sh[4];
  float s = 0.f;
  for (int i = threadIdx.x; i < MCOLS; i += 256) s += psi[i];
  #pragma unroll
  for (int m = 32; m >= 1; m >>= 1) s += __shfl_xor(s, m);
  const int wid = threadIdx.x >> 6, lane = threadIdx.x & 63;
  if (lane == 0) sh[wid] = s;
  __syncthreads();
  if (threadIdx.x == 0)
    out[0] = sum_accum[0] / (float)NROWS + (sh[0] + sh[1] + sh[2] + sh[3]) / (float)MCOLS;
}

extern "C" void kernel_launch(void* const* d_in, const int* in_sizes, int n_in,
                              void* d_out, int out_size, void* d_ws, size_t ws_size,
                              hipStream_t stream)
{
  const float* X   = (const float*)d_in[0];
  const float* Y   = (const float*)d_in[1];
  const float* psi = (const float*)d_in[2];
  float* out = (float*)d_out;

  char* ws = (char*)d_ws;
  uint32_t* XqN    = (uint32_t*)(ws);                                           // 8,388,608 B
  uint32_t* Yq     = (uint32_t*)(ws + (size_t)NROWS * DDIM);                    // 2,097,152 B
  float* cbuf      = (float*)(ws + (size_t)(NROWS + MCOLS) * DDIM);             //    32,768 B
  float* xhalf     = (float*)((char*)cbuf + (size_t)MCOLS * 4);                 //   131,072 B
  float* sum_accum = (float*)((char*)xhalf + (size_t)NROWS * 4);                //         4 B

  k_prep <<<2048, 256, 0, stream>>>(X, Y, psi, XqN, Yq, xhalf, cbuf, sum_accum);
  k_gemm <<<NWG, 512, 0, stream>>>(XqN, Yq, cbuf, xhalf, sum_accum);
  k_final<<<1, 256, 0, stream>>>(psi, sum_accum, out);
}